// Round 7
// baseline (616.088 us; speedup 1.0000x reference)
//
#include <hip/hip_runtime.h>

#define N_NODES 50000
#define HIDDEN  64
#define N_EDGES 1200000

#define BSHIFT 7                       // 128 nodes per bucket
#define BUKSZ  128
#define NBUK   391                     // ceil(50000/128)
#define ABLK   512                     // scatter blocks (block-local sort)
#define CH     2344                    // ceil(N_EDGES/ABLK) edges per slice
#define PAD2   4096                    // padded csr capacity per bucket (avg 3072, ~18 sigma)
#define FBLK   1024                    // fused-layer grid
#define NW     (FBLK * 4)              // fused-layer wave count (256-thread blocks)

__device__ __forceinline__ float bcastf(float v, int k) {
    return __int_as_float(__builtin_amdgcn_readlane(__float_as_int(v), k));
}
__device__ __forceinline__ unsigned f2bf(float x) {   // f32 -> bf16 (RNE)
    unsigned u = __float_as_uint(x);
    u += 0x7fffu + ((u >> 16) & 1u);
    return u >> 16;
}
__device__ __forceinline__ float bfl(unsigned w) { return __uint_as_float(w << 16); }
__device__ __forceinline__ float bfh(unsigned w) { return __uint_as_float(w & 0xffff0000u); }
__device__ __forceinline__ void bfly(float4& a) {     // butterfly: all lanes get group-sum
    a.x += __shfl_xor(a.x, 16); a.y += __shfl_xor(a.y, 16);
    a.z += __shfl_xor(a.z, 16); a.w += __shfl_xor(a.w, 16);
    a.x += __shfl_xor(a.x, 32); a.y += __shfl_xor(a.y, 32);
    a.z += __shfl_xor(a.z, 32); a.w += __shfl_xor(a.w, 32);
}

// ---------------- Kernel A: block-local bucket sort (pure stores) + W packing ----------------
__global__ __launch_bounds__(512) void build_a_kernel(const int* __restrict__ ei,
                                                      int* __restrict__ tmp,
                                                      int* __restrict__ starts_m,
                                                      int* __restrict__ counts_m,
                                                      const float* __restrict__ Wn2, const float* __restrict__ Ws2,
                                                      const float* __restrict__ Wn3, const float* __restrict__ Ws3,
                                                      const float* __restrict__ Wn4, const float* __restrict__ Ws4,
                                                      uint4* __restrict__ pw) {
    __shared__ int hist[NBUK];
    __shared__ int cur[NBUK];
    __shared__ int stage[CH];
    int b = blockIdx.x, tid = threadIdx.x;
    if (b < ABLK) {
        int base = b * CH;
        int cnt = N_EDGES - base; if (cnt > CH) cnt = CH;
        for (int i = tid; i < NBUK; i += 512) hist[i] = 0;
        __syncthreads();
        for (int i = tid; i < cnt; i += 512)
            atomicAdd(&hist[ei[N_EDGES + base + i] >> BSHIFT], 1);
        __syncthreads();
        int v = (tid < NBUK) ? hist[tid] : 0;
#pragma unroll
        for (int o = 1; o < NBUK; o <<= 1) {           // Hillis-Steele inclusive
            __syncthreads();
            int y = (tid >= o && tid < NBUK) ? hist[tid - o] : 0;
            __syncthreads();
            if (tid < NBUK) hist[tid] += y;
        }
        __syncthreads();
        if (tid < NBUK) {
            int excl = hist[tid] - v;
            cur[tid] = excl;
            starts_m[tid * ABLK + b] = base + excl;    // global tmp position of this segment
            counts_m[tid * ABLK + b] = v;
        }
        __syncthreads();
        for (int i = tid; i < cnt; i += 512) {
            int src = ei[base + i];
            int dst = ei[N_EDGES + base + i];
            int p = atomicAdd(&cur[dst >> BSHIFT], 1);
            stage[p] = src | ((dst & (BUKSZ - 1)) << 16);
        }
        __syncthreads();
        for (int i = tid; i < cnt; i += 512) tmp[base + i] = stage[i];
    } else {
        // pack W_nbr/W_self of layers 2..4 into bf16-interleaved uint4: [layer][k*16+q]
        int layer = b - ABLK;
        const float* Wn = (layer == 0) ? Wn2 : (layer == 1) ? Wn3 : Wn4;
        const float* Ws = (layer == 0) ? Ws2 : (layer == 1) ? Ws3 : Ws4;
        for (int e = tid; e < 1024; e += 512) {
            const float4 a = *(const float4*)(Wn + e * 4);
            const float4 c = *(const float4*)(Ws + e * 4);
            uint4 o;
            o.x = f2bf(a.x) | (f2bf(a.y) << 16);
            o.y = f2bf(a.z) | (f2bf(a.w) << 16);
            o.z = f2bf(c.x) | (f2bf(c.y) << 16);
            o.w = f2bf(c.z) | (f2bf(c.w) << 16);
            pw[layer * 1024 + e] = o;
        }
    }
}

// ---------------- Kernel B: per-bucket counting sort (blocks 0..390) + gemm1 (rest) ----------------
__global__ __launch_bounds__(512) void build_b_kernel(const int* __restrict__ tmp,
                                                      const int* __restrict__ starts_m,
                                                      const int* __restrict__ counts_m,
                                                      int2* __restrict__ row_info,
                                                      unsigned short* __restrict__ csr,
                                                      const float* __restrict__ x,
                                                      const float* __restrict__ Wrel,
                                                      const float* __restrict__ Wroot,
                                                      const float* __restrict__ bias,
                                                      unsigned short* __restrict__ tbf,
                                                      float* __restrict__ u) {
    __shared__ int sl[ABLK];
    __shared__ int cl[ABLK];
    __shared__ int hist[BUKSZ];
    __shared__ int cur[BUKSZ];
    __shared__ unsigned short stage[PAD2];
    int b = blockIdx.x, tid = threadIdx.x;
    if (b < NBUK) {
        sl[tid] = starts_m[b * ABLK + tid];
        cl[tid] = counts_m[b * ABLK + tid];
        if (tid < BUKSZ) hist[tid] = 0;
        __syncthreads();
        {   // thread-per-segment histogram
            int s = sl[tid], c = cl[tid];
            for (int i = 0; i < c; ++i) atomicAdd(&hist[tmp[s + i] >> 16], 1);
        }
        __syncthreads();
        int v = (tid < BUKSZ) ? hist[tid] : 0;
#pragma unroll
        for (int o = 1; o < BUKSZ; o <<= 1) {
            __syncthreads();
            int y = (tid >= o && tid < BUKSZ) ? hist[tid - o] : 0;
            __syncthreads();
            if (tid < BUKSZ) hist[tid] += y;
        }
        __syncthreads();
        if (tid < BUKSZ) {
            int excl = hist[tid] - v;
            cur[tid] = excl;
            int node = (b << BSHIFT) + tid;
            if (node < N_NODES) row_info[node] = make_int2(b * PAD2 + excl, v);
        }
        __syncthreads();
        {   // thread-per-segment placement
            int s = sl[tid], c = cl[tid];
            for (int i = 0; i < c; ++i) {
                int p = tmp[s + i];
                int slot = atomicAdd(&cur[p >> 16], 1);
                stage[slot] = (unsigned short)(p & 0xFFFF);
            }
        }
        __syncthreads();
        int total = hist[BUKSZ - 1];
        for (int i = tid; i < total; i += 512) csr[b * PAD2 + i] = stage[i];
    } else {
        // gemm1: t1 = x@Wrel (bf16), u1 = x@Wroot + b1  (register-held W, readlane bcast)
        int lane = tid & 63;
        float wn[64], ws[64];
#pragma unroll
        for (int k = 0; k < 64; ++k) {
            wn[k] = Wrel[k * 64 + lane];
            ws[k] = Wroot[k * 64 + lane];
        }
        float bv = bias[lane];
        int wave = (b - NBUK) * 8 + (tid >> 6);
        int nwaves = (gridDim.x - NBUK) * 8;
        if (wave == 0) tbf[(size_t)N_NODES * 64 + lane] = 0;   // zero padding row
        for (int i = wave; i < N_NODES; i += nwaves) {
            float hv = x[i * 64 + lane];
            float tacc = 0.f, uacc = bv;
#pragma unroll
            for (int k = 0; k < 64; ++k) {
                float hk = bcastf(hv, k);
                tacc = fmaf(hk, wn[k], tacc);
                uacc = fmaf(hk, ws[k], uacc);
            }
            tbf[(size_t)i * 64 + lane] = (unsigned short)f2bf(tacc);
            u[(size_t)i * 64 + lane] = uacc;
        }
    }
}

// ---------------- per-node gather-aggregate (MLP=8) + epilogue -> h row (4ch/lane) ----------------
__device__ __forceinline__ float4 agg_node(const unsigned short* __restrict__ tin,
                                           const float* __restrict__ uin,
                                           const int2* __restrict__ row_info,
                                           const unsigned short* __restrict__ csr,
                                           int node, int lane, int g, int q, int use_mean) {
    if (node >= N_NODES) return make_float4(0.f, 0.f, 0.f, 0.f);
    int2 ri = row_info[node];
    int start = ri.x, deg = ri.y;
    float4 a0{0,0,0,0}, a1{0,0,0,0}, a2{0,0,0,0}, a3{0,0,0,0};
    float4 a4{0,0,0,0}, a5{0,0,0,0}, a6{0,0,0,0}, a7{0,0,0,0};
    for (int e = 0; e < deg; e += 64) {
        int cnt = deg - e; if (cnt > 64) cnt = 64;
        int idx = (lane < cnt) ? (int)csr[start + e + lane] : N_NODES;  // zero row
        int cnt32 = (cnt + 31) & ~31;
        for (int j = 0; j < cnt32; j += 32) {
            int s0 = __shfl(idx, j + g);
            int s1 = __shfl(idx, j + 4 + g);
            int s2 = __shfl(idx, j + 8 + g);
            int s3 = __shfl(idx, j + 12 + g);
            int s4 = __shfl(idx, j + 16 + g);
            int s5 = __shfl(idx, j + 20 + g);
            int s6 = __shfl(idx, j + 24 + g);
            int s7 = __shfl(idx, j + 28 + g);
            const uint2 w0 = *(const uint2*)(tin + (size_t)s0 * 64 + q * 4);
            const uint2 w1 = *(const uint2*)(tin + (size_t)s1 * 64 + q * 4);
            const uint2 w2 = *(const uint2*)(tin + (size_t)s2 * 64 + q * 4);
            const uint2 w3 = *(const uint2*)(tin + (size_t)s3 * 64 + q * 4);
            const uint2 w4 = *(const uint2*)(tin + (size_t)s4 * 64 + q * 4);
            const uint2 w5 = *(const uint2*)(tin + (size_t)s5 * 64 + q * 4);
            const uint2 w6 = *(const uint2*)(tin + (size_t)s6 * 64 + q * 4);
            const uint2 w7 = *(const uint2*)(tin + (size_t)s7 * 64 + q * 4);
            a0.x += bfl(w0.x); a0.y += bfh(w0.x); a0.z += bfl(w0.y); a0.w += bfh(w0.y);
            a1.x += bfl(w1.x); a1.y += bfh(w1.x); a1.z += bfl(w1.y); a1.w += bfh(w1.y);
            a2.x += bfl(w2.x); a2.y += bfh(w2.x); a2.z += bfl(w2.y); a2.w += bfh(w2.y);
            a3.x += bfl(w3.x); a3.y += bfh(w3.x); a3.z += bfl(w3.y); a3.w += bfh(w3.y);
            a4.x += bfl(w4.x); a4.y += bfh(w4.x); a4.z += bfl(w4.y); a4.w += bfh(w4.y);
            a5.x += bfl(w5.x); a5.y += bfh(w5.x); a5.z += bfl(w5.y); a5.w += bfh(w5.y);
            a6.x += bfl(w6.x); a6.y += bfh(w6.x); a6.z += bfl(w6.y); a6.w += bfh(w6.y);
            a7.x += bfl(w7.x); a7.y += bfh(w7.x); a7.z += bfl(w7.y); a7.w += bfh(w7.y);
        }
    }
    float4 acc;
    acc.x = ((a0.x + a1.x) + (a2.x + a3.x)) + ((a4.x + a5.x) + (a6.x + a7.x));
    acc.y = ((a0.y + a1.y) + (a2.y + a3.y)) + ((a4.y + a5.y) + (a6.y + a7.y));
    acc.z = ((a0.z + a1.z) + (a2.z + a3.z)) + ((a4.z + a5.z) + (a6.z + a7.z));
    acc.w = ((a0.w + a1.w) + (a2.w + a3.w)) + ((a4.w + a5.w) + (a6.w + a7.w));
    bfly(acc);
    float sc = use_mean ? 1.f / fmaxf((float)deg, 1.f) : 1.f;
    const float4 uv = *(const float4*)(uin + (size_t)node * 64 + q * 4);
    float4 h;
    h.x = fmaxf(uv.x + acc.x * sc, 0.f);
    h.y = fmaxf(uv.y + acc.y * sc, 0.f);
    h.z = fmaxf(uv.z + acc.z * sc, 0.f);
    h.w = fmaxf(uv.w + acc.w * sc, 0.f);
    return h;
}

// ---------------- fused layer: agg(layer k) [+ optional out write] [+ gemm(layer k+1)] ----------------
__global__ __launch_bounds__(256) void fused_kernel(const unsigned short* __restrict__ tin,
                                                    const float* __restrict__ uin,
                                                    const int2* __restrict__ row_info,
                                                    const unsigned short* __restrict__ csr,
                                                    const uint4* __restrict__ pwL,
                                                    const float* __restrict__ bias_next,
                                                    unsigned short* __restrict__ tout,
                                                    float* __restrict__ uout,
                                                    float* __restrict__ dout,
                                                    int use_mean, int do_gemm) {
    __shared__ uint4 wlds[1024];   // packed W_nbr|W_self bf16, 16 KB
    __shared__ float blds[64];
    int tid = threadIdx.x;
    if (do_gemm) {
        for (int i = tid; i < 1024; i += 256) wlds[i] = pwL[i];
        if (tid < 64) blds[tid] = bias_next[tid];
        if (blockIdx.x == 0 && tid < 32)     // zero padding row of tout (128 ushorts)
            ((uint4*)(tout + (size_t)N_NODES * 64))[tid % 8 + (tid / 8) * 0] = make_uint4(0,0,0,0);
        if (blockIdx.x == 0 && tid < 64)
            ((unsigned int*)(tout + (size_t)N_NODES * 64))[tid] = 0;
    }
    __syncthreads();
    int lane = tid & 63, g = lane >> 4, q = lane & 15;
    int w = blockIdx.x * 4 + (tid >> 6);   // wave id 0..NW-1

#pragma unroll
    for (int bi = 0; bi < 4; ++bi) {       // 4 batches x 4 nodes = 16 strided nodes/wave
        int nodes[4];
        float4 h4[4];
#pragma unroll
        for (int i = 0; i < 4; ++i) {
            int node = w + NW * (bi * 4 + i);
            nodes[i] = node;
            h4[i] = agg_node(tin, uin, row_info, csr, node, lane, g, q, use_mean);
            if (dout && node < N_NODES && g == 0)
                *(float4*)(dout + (size_t)node * 64 + q * 4) = h4[i];
        }
        if (!do_gemm) continue;
        // fused gemm: group g covers k in [16g, 16g+16); batch of 4 nodes shares each W row read
        float4 tp[4] = {{0,0,0,0},{0,0,0,0},{0,0,0,0},{0,0,0,0}};
        float4 up[4] = {{0,0,0,0},{0,0,0,0},{0,0,0,0},{0,0,0,0}};
#pragma unroll
        for (int j = 0; j < 16; ++j) {
            uint4 wv = wlds[(16 * g + j) * 16 + q];
            float wn0 = bfl(wv.x), wn1 = bfh(wv.x), wn2 = bfl(wv.y), wn3 = bfh(wv.y);
            float ws0 = bfl(wv.z), ws1 = bfh(wv.z), ws2 = bfl(wv.w), ws3 = bfh(wv.w);
            int src = g * 4 + (j >> 2);    // lane holding channel k=16g+j (group-0 copy)
#pragma unroll
            for (int i = 0; i < 4; ++i) {
                float hk;
                if ((j & 3) == 0)      hk = __shfl(h4[i].x, src);
                else if ((j & 3) == 1) hk = __shfl(h4[i].y, src);
                else if ((j & 3) == 2) hk = __shfl(h4[i].z, src);
                else                   hk = __shfl(h4[i].w, src);
                tp[i].x = fmaf(hk, wn0, tp[i].x); tp[i].y = fmaf(hk, wn1, tp[i].y);
                tp[i].z = fmaf(hk, wn2, tp[i].z); tp[i].w = fmaf(hk, wn3, tp[i].w);
                up[i].x = fmaf(hk, ws0, up[i].x); up[i].y = fmaf(hk, ws1, up[i].y);
                up[i].z = fmaf(hk, ws2, up[i].z); up[i].w = fmaf(hk, ws3, up[i].w);
            }
        }
#pragma unroll
        for (int i = 0; i < 4; ++i) {
            bfly(tp[i]); bfly(up[i]);
            if (nodes[i] < N_NODES && g == 0) {
                const float4 bv = *(const float4*)&blds[q * 4];
                float4 uo;
                uo.x = up[i].x + bv.x; uo.y = up[i].y + bv.y;
                uo.z = up[i].z + bv.z; uo.w = up[i].w + bv.w;
                *(float4*)(uout + (size_t)nodes[i] * 64 + q * 4) = uo;
                uint2 tpk;
                tpk.x = f2bf(tp[i].x) | (f2bf(tp[i].y) << 16);
                tpk.y = f2bf(tp[i].z) | (f2bf(tp[i].w) << 16);
                *(uint2*)(tout + (size_t)nodes[i] * 64 + q * 4) = tpk;
            }
        }
    }
}

// ---------------- launch ----------------
extern "C" void kernel_launch(void* const* d_in, const int* in_sizes, int n_in,
                              void* d_out, int out_size, void* d_ws, size_t ws_size,
                              hipStream_t stream) {
    const float* x      = (const float*)d_in[0];
    const int*   ei     = (const int*)d_in[1];
    const float* Wrel1  = (const float*)d_in[2];
    const float* Wroot1 = (const float*)d_in[3];
    const float* b1     = (const float*)d_in[4];
    const float* Wself2 = (const float*)d_in[5];
    const float* Wnbr2  = (const float*)d_in[6];
    const float* b2     = (const float*)d_in[7];
    const float* Wself3 = (const float*)d_in[8];
    const float* Wnbr3  = (const float*)d_in[9];
    const float* b3     = (const float*)d_in[10];
    const float* Wself4 = (const float*)d_in[11];
    const float* Wnbr4  = (const float*)d_in[12];
    const float* b4     = (const float*)d_in[13];

    const int N = N_NODES;

    auto align = [](size_t o) { return (o + 255) & ~(size_t)255; };
    char* base = (char*)d_ws;
    size_t off = 0;
    int*  tmp      = (int*)(base + off);  off = align(off + (size_t)ABLK * CH * 4);
    int*  starts_m = (int*)(base + off);  off = align(off + (size_t)NBUK * ABLK * 4);
    int*  counts_m = (int*)(base + off);  off = align(off + (size_t)NBUK * ABLK * 4);
    int2* row_info = (int2*)(base + off); off = align(off + (size_t)N * 8);
    unsigned short* csr = (unsigned short*)(base + off); off = align(off + (size_t)NBUK * PAD2 * 2);
    uint4* pw = (uint4*)(base + off);     off = align(off + (size_t)3 * 1024 * 16);
    unsigned short* tbA = (unsigned short*)(base + off); off = align(off + (size_t)(N + 1) * 64 * 2);
    unsigned short* tbB = (unsigned short*)(base + off); off = align(off + (size_t)(N + 1) * 64 * 2);
    float* uA = (float*)(base + off); off = align(off + (size_t)N * 64 * 4);
    float* uB = (float*)(base + off); off = align(off + (size_t)N * 64 * 4);

    float* out1 = (float*)d_out;
    float* out2 = (float*)d_out + (size_t)N * 64;

    // A: block-local bucket sort + W packing        (1 dispatch)
    build_a_kernel<<<ABLK + 3, 512, 0, stream>>>(ei, tmp, starts_m, counts_m,
                                                 Wnbr2, Wself2, Wnbr3, Wself3, Wnbr4, Wself4, pw);
    // B: per-bucket counting sort || gemm1 from x   (1 dispatch)
    build_b_kernel<<<NBUK + 1024, 512, 0, stream>>>(tmp, starts_m, counts_m, row_info, csr,
                                                    x, Wrel1, Wroot1, b1, tbA, uA);
    // F1: agg L1 (mean) -> gemm L2                  (t1,u1 -> t2,u2)
    fused_kernel<<<FBLK, 256, 0, stream>>>(tbA, uA, row_info, csr, pw,        b2, tbB, uB, nullptr, 1, 1);
    // F2: agg L2 -> out1, gemm L3                   (t2,u2 -> t3,u3)
    fused_kernel<<<FBLK, 256, 0, stream>>>(tbB, uB, row_info, csr, pw + 1024, b3, tbA, uA, out1, 0, 1);
    // F3: agg L3 -> gemm L4                         (t3,u3 -> t4,u4)
    fused_kernel<<<FBLK, 256, 0, stream>>>(tbA, uA, row_info, csr, pw + 2048, b4, tbB, uB, nullptr, 0, 1);
    // F4: agg L4 -> out2
    fused_kernel<<<FBLK, 256, 0, stream>>>(tbB, uB, row_info, csr, nullptr, nullptr, nullptr, nullptr, out2, 0, 0);
}

// Round 8
// 325.374 us; speedup vs baseline: 1.8935x; 1.8935x over previous
//
#include <hip/hip_runtime.h>

#define N_NODES 50000
#define HIDDEN  64
#define N_EDGES 1200000

#define BSHIFT 7                      // 128 nodes per bucket
#define BUKSZ  128
#define NBUK   391                    // ceil(50000/128)
#define GBIN   256                    // scatter blocks
#define PAD2   4096                   // padded capacity per bucket (avg 3072+align pad ~3456)

__device__ __forceinline__ float bcastf(float v, int k) {
    return __int_as_float(__builtin_amdgcn_readlane(__float_as_int(v), k));
}
__device__ __forceinline__ unsigned short f2bf(float x) {   // f32 -> bf16 RNE
    unsigned u = __float_as_uint(x);
    u += 0x7fffu + ((u >> 16) & 1u);
    return (unsigned short)(u >> 16);
}
__device__ __forceinline__ float bfl(unsigned w) { return __uint_as_float(w << 16); }
__device__ __forceinline__ float bfh(unsigned w) { return __uint_as_float(w & 0xffff0000u); }

// ---------------- bucketed CSR build (R6-proven) ----------------

__global__ __launch_bounds__(512) void init_kernel(int* __restrict__ cursor) {
    int tid = threadIdx.x;
    if (tid < NBUK) cursor[tid] = tid * PAD2;
}

__global__ __launch_bounds__(256) void scatter_fused_kernel(const int* __restrict__ ei,
                                                            int* __restrict__ cursor,
                                                            int* __restrict__ tmp, int E) {
    __shared__ int h[NBUK];
    __shared__ int cur[NBUK];
    int tid = threadIdx.x;
    for (int b = tid; b < NBUK; b += 256) h[b] = 0;
    __syncthreads();
    for (int e = blockIdx.x * 256 + tid; e < E; e += GBIN * 256)
        atomicAdd(&h[ei[E + e] >> BSHIFT], 1);
    __syncthreads();
    for (int b = tid; b < NBUK; b += 256) cur[b] = atomicAdd(&cursor[b], h[b]);
    __syncthreads();
    for (int e = blockIdx.x * 256 + tid; e < E; e += GBIN * 256) {
        int src = ei[e];
        int dst = ei[E + e];
        int p = atomicAdd(&cur[dst >> BSHIFT], 1);
        tmp[p] = src | ((dst & (BUKSZ - 1)) << 16);
    }
}

// one 512-thread block per bucket: LDS hist(128) -> 4-aligned scan -> counting sort -> csr
__global__ __launch_bounds__(512) void bucketize_kernel(const int* __restrict__ tmp,
                                                        const int* __restrict__ cursor,
                                                        int2* __restrict__ row_info,
                                                        unsigned short* __restrict__ csr,
                                                        int n) {
    __shared__ int hist[BUKSZ];
    __shared__ int cur[BUKSZ];
    __shared__ unsigned short stage[PAD2];
    int b = blockIdx.x, tid = threadIdx.x;
    int base = b * PAD2;
    int count = cursor[b] - base;
    int node_base = b << BSHIFT;

    if (tid < BUKSZ) hist[tid] = 0;
    __syncthreads();
    for (int i = tid; i < count; i += 512)
        atomicAdd(&hist[tmp[base + i] >> 16], 1);
    __syncthreads();
    int v = (tid < BUKSZ) ? hist[tid] : 0;
    int vr = (v + 3) & ~3;                   // 4-aligned per-node segment
    __syncthreads();
    if (tid < BUKSZ) hist[tid] = vr;
#pragma unroll
    for (int o = 1; o < BUKSZ; o <<= 1) {    // Hillis-Steele inclusive scan of vr
        __syncthreads();
        int y = (tid >= o && tid < BUKSZ) ? hist[tid - o] : 0;
        __syncthreads();
        if (tid < BUKSZ) hist[tid] += y;
    }
    __syncthreads();
    if (tid < BUKSZ) {
        int excl = hist[tid] - vr;           // 4-aligned start
        cur[tid] = excl;
        int node = node_base + tid;
        if (node < n) row_info[node] = make_int2(base + excl, v);
    }
    __syncthreads();
    for (int i = tid; i < count; i += 512) {
        int p = tmp[base + i];
        int slot = atomicAdd(&cur[p >> 16], 1);
        stage[slot] = (unsigned short)(p & 0xFFFF);
    }
    __syncthreads();
    int total = hist[BUKSZ - 1];             // rounded total (pad slots = garbage, clamped on use)
    for (int i = tid; i < total; i += 512)
        csr[base + i] = stage[i];
}

// ---------------- dense GEMMs: t(bf16) = h@Wnbr ; u = h@Wself + b (R6-proven) ----------------
__global__ __launch_bounds__(256) void gemm2_kernel(const float* __restrict__ h,
                                                    const float* __restrict__ Wnbr,
                                                    const float* __restrict__ Wself,
                                                    const float* __restrict__ bias,
                                                    unsigned short* __restrict__ tbf,
                                                    float* __restrict__ u, int n) {
    int lane = threadIdx.x & 63;
    float wn[64], ws[64];
#pragma unroll
    for (int k = 0; k < 64; ++k) {
        wn[k] = Wnbr[k * 64 + lane];
        ws[k] = Wself[k * 64 + lane];
    }
    float bv = bias[lane];
    int wave = (blockIdx.x * 256 + threadIdx.x) >> 6;
    int nwaves = gridDim.x * 4;
    if (wave == 0) tbf[(size_t)n * 64 + lane] = 0;   // zero row n (clamp target)
    for (int i = wave; i < n; i += nwaves) {
        float hv = h[i * 64 + lane];
        float tacc = 0.f, uacc = bv;
#pragma unroll
        for (int k = 0; k < 64; ++k) {
            float hk = bcastf(hv, k);
            tacc = fmaf(hk, wn[k], tacc);
            uacc = fmaf(hk, ws[k], uacc);
        }
        tbf[(size_t)i * 64 + lane] = f2bf(tacc);
        u[(size_t)i * 64 + lane] = uacc;
    }
}

// ---------------- gather-aggregate + epilogue (shfl-free inner loop) ----------------
// one wave per node; group g (16 lanes) owns contiguous edge-quads [base+4g, base+4g+4).
// Per iter: 1 independent 8B idx load + 4 independent row loads; no cross-lane deps.
__global__ __launch_bounds__(256, 8) void agg_kernel(const unsigned short* __restrict__ tbf,
                                                     const float* __restrict__ u,
                                                     const int2* __restrict__ row_info,
                                                     const unsigned short* __restrict__ csr,
                                                     float* __restrict__ out, int n, int use_mean) {
    int lane = threadIdx.x & 63;
    int g = lane >> 4;          // edge-quad subgroup 0..3
    int q = lane & 15;          // channel quad
    int node = (blockIdx.x * 256 + threadIdx.x) >> 6;
    if (node >= n) return;
    int2 ri = row_info[node];
    int start = ri.x, deg = ri.y;      // start is 4-aligned
    const unsigned short* cp = csr + start;
    float4 a0{0,0,0,0}, a1{0,0,0,0}, a2{0,0,0,0}, a3{0,0,0,0};
    for (int base = 0; base < deg; base += 16) {
        int m = base + 4 * g;
        const uint2 iv = *(const uint2*)(cp + m);      // 4 packed ushort idx (8B aligned)
        int s0 = (m + 0 < deg) ? (int)(iv.x & 0xFFFF) : n;
        int s1 = (m + 1 < deg) ? (int)(iv.x >> 16)    : n;
        int s2 = (m + 2 < deg) ? (int)(iv.y & 0xFFFF) : n;
        int s3 = (m + 3 < deg) ? (int)(iv.y >> 16)    : n;
        const uint2 w0 = *(const uint2*)(tbf + (size_t)s0 * 64 + q * 4);
        const uint2 w1 = *(const uint2*)(tbf + (size_t)s1 * 64 + q * 4);
        const uint2 w2 = *(const uint2*)(tbf + (size_t)s2 * 64 + q * 4);
        const uint2 w3 = *(const uint2*)(tbf + (size_t)s3 * 64 + q * 4);
        a0.x += bfl(w0.x); a0.y += bfh(w0.x); a0.z += bfl(w0.y); a0.w += bfh(w0.y);
        a1.x += bfl(w1.x); a1.y += bfh(w1.x); a1.z += bfl(w1.y); a1.w += bfh(w1.y);
        a2.x += bfl(w2.x); a2.y += bfh(w2.x); a2.z += bfl(w2.y); a2.w += bfh(w2.y);
        a3.x += bfl(w3.x); a3.y += bfh(w3.x); a3.z += bfl(w3.y); a3.w += bfh(w3.y);
    }
    float4 acc;
    acc.x = (a0.x + a1.x) + (a2.x + a3.x);
    acc.y = (a0.y + a1.y) + (a2.y + a3.y);
    acc.z = (a0.z + a1.z) + (a2.z + a3.z);
    acc.w = (a0.w + a1.w) + (a2.w + a3.w);
    // reduce across the 4 edge-quad groups
    acc.x += __shfl_xor(acc.x, 16); acc.y += __shfl_xor(acc.y, 16);
    acc.z += __shfl_xor(acc.z, 16); acc.w += __shfl_xor(acc.w, 16);
    acc.x += __shfl_xor(acc.x, 32); acc.y += __shfl_xor(acc.y, 32);
    acc.z += __shfl_xor(acc.z, 32); acc.w += __shfl_xor(acc.w, 32);

    float scale = use_mean ? 1.f / fmaxf((float)deg, 1.f) : 1.f;
    if (g == 0) {
        const float4 uv = *(const float4*)(u + (size_t)node * 64 + q * 4);
        float4 r;
        r.x = fmaxf(uv.x + acc.x * scale, 0.f);
        r.y = fmaxf(uv.y + acc.y * scale, 0.f);
        r.z = fmaxf(uv.z + acc.z * scale, 0.f);
        r.w = fmaxf(uv.w + acc.w * scale, 0.f);
        *(float4*)(out + (size_t)node * 64 + q * 4) = r;
    }
}

// ---------------- launch ----------------

extern "C" void kernel_launch(void* const* d_in, const int* in_sizes, int n_in,
                              void* d_out, int out_size, void* d_ws, size_t ws_size,
                              hipStream_t stream) {
    const float* x      = (const float*)d_in[0];
    const int*   ei     = (const int*)d_in[1];
    const float* Wrel1  = (const float*)d_in[2];
    const float* Wroot1 = (const float*)d_in[3];
    const float* b1     = (const float*)d_in[4];
    const float* Wself2 = (const float*)d_in[5];
    const float* Wnbr2  = (const float*)d_in[6];
    const float* b2     = (const float*)d_in[7];
    const float* Wself3 = (const float*)d_in[8];
    const float* Wnbr3  = (const float*)d_in[9];
    const float* b3     = (const float*)d_in[10];
    const float* Wself4 = (const float*)d_in[11];
    const float* Wnbr4  = (const float*)d_in[12];
    const float* b4     = (const float*)d_in[13];

    const int N = N_NODES, E = N_EDGES;

    auto align = [](size_t o) { return (o + 255) & ~(size_t)255; };
    char* base = (char*)d_ws;
    size_t off = 0;
    int*  cursor   = (int*)(base + off);  off = align(off + (size_t)NBUK * 4);
    int2* row_info = (int2*)(base + off); off = align(off + (size_t)N * 8);
    int*  tmp      = (int*)(base + off);  off = align(off + (size_t)NBUK * PAD2 * 4);
    unsigned short* csr = (unsigned short*)(base + off); off = align(off + (size_t)NBUK * PAD2 * 2 + 256);
    unsigned short* tbf = (unsigned short*)(base + off); off = align(off + (size_t)(N + 1) * 64 * 2);
    float* u  = (float*)(base + off); off = align(off + (size_t)N * 64 * 4);
    float* h1 = (float*)(base + off); off = align(off + (size_t)N * 64 * 4);

    float* out1 = (float*)d_out;
    float* out2 = (float*)d_out + (size_t)N * 64;

    // ---- CSR build: 3 dispatches ----
    init_kernel<<<1, 512, 0, stream>>>(cursor);
    scatter_fused_kernel<<<GBIN, 256, 0, stream>>>(ei, cursor, tmp, E);
    bucketize_kernel<<<NBUK, 512, 0, stream>>>(tmp, cursor, row_info, csr, N);

    const int GB = 768;            // gemm blocks (3072 waves)
    const int AB = (N + 3) / 4;    // 12500 blocks = 50000 waves (1 node/wave)

    // Layer 1 (RGCN): u = x@W_root1 + b1 ; t = x@W_rel1 ; mean aggregate
    gemm2_kernel<<<GB, 256, 0, stream>>>(x, Wrel1, Wroot1, b1, tbf, u, N);
    agg_kernel<<<AB, 256, 0, stream>>>(tbf, u, row_info, csr, h1, N, 1);
    // Layer 2 (GraphConv) -> x_1
    gemm2_kernel<<<GB, 256, 0, stream>>>(h1, Wnbr2, Wself2, b2, tbf, u, N);
    agg_kernel<<<AB, 256, 0, stream>>>(tbf, u, row_info, csr, out1, N, 0);
    // Layer 3
    gemm2_kernel<<<GB, 256, 0, stream>>>(out1, Wnbr3, Wself3, b3, tbf, u, N);
    agg_kernel<<<AB, 256, 0, stream>>>(tbf, u, row_info, csr, h1, N, 0);
    // Layer 4 -> x_2
    gemm2_kernel<<<GB, 256, 0, stream>>>(h1, Wnbr4, Wself4, b4, tbf, u, N);
    agg_kernel<<<AB, 256, 0, stream>>>(tbf, u, row_info, csr, out2, N, 0);
}